// Round 13
// baseline (781.317 us; speedup 1.0000x reference)
//
#include <hip/hip_runtime.h>

typedef __attribute__((ext_vector_type(8))) short bf16x8;   // 8 bf16 = 4 VGPRs
typedef __attribute__((ext_vector_type(4))) float f32x4;    // MFMA C/D

__device__ __forceinline__ float bf2f(unsigned short u){
    unsigned int v = ((unsigned int)u) << 16;
    return __builtin_bit_cast(float, v);
}
__device__ __forceinline__ unsigned short f2bf(float f){
    unsigned int u = __builtin_bit_cast(unsigned int, f);
    u += 0x7FFFu + ((u >> 16) & 1u);   // RTNE (no NaN inputs here)
    return (unsigned short)(u >> 16);
}
// HW packed f32->bf16 RTNE (verified correct rounds 3/6/8/10)
__device__ __forceinline__ unsigned int cvt_pk_bf16(float lo, float hi){
    unsigned int r;
    asm("v_cvt_pk_bf16_f32 %0, %1, %2" : "=v"(r) : "v"(lo), "v"(hi));
    return r;
}
__device__ __forceinline__ unsigned int mulpack(unsigned int u, float xf){
    float flo = __builtin_bit_cast(float, u << 16);
    float fhi = __builtin_bit_cast(float, u & 0xffff0000u);
    return cvt_pk_bf16(xf * flo, xf * fhi);
}

// ---- prep: W (K x 256) fp32 -> Wt (256 x K) bf16, LDS-tiled transpose ----
__global__ void prep_wt(const float* __restrict__ W, unsigned short* __restrict__ Wt, int K){
    __shared__ float tile[64][65];
    const int k0 = blockIdx.x * 64;
    const int j0 = blockIdx.y * 64;
    const int t  = threadIdx.x;              // 256
    #pragma unroll
    for (int it = 0; it < 16; it++){
        int idx = it * 256 + t;
        int kr = idx >> 6, jc = idx & 63;
        tile[kr][jc] = W[(size_t)(k0 + kr) * 256 + j0 + jc];
    }
    __syncthreads();
    #pragma unroll
    for (int it = 0; it < 2; it++){
        int idx = it * 256 + t;
        int jr = idx >> 3, kc = (idx & 7) << 3;
        uint4 tv;
        unsigned short* ts = (unsigned short*)&tv;
        #pragma unroll
        for (int q = 0; q < 8; q++)
            ts[q] = f2bf(tile[kc + q][jr]);
        *(uint4*)(Wt + (size_t)(j0 + jr) * K + k0 + kc) = tv;
    }
}

// ---- prep: x (b,m,d) fp32 -> Xt[b][d][m] bf16 ----
__global__ void prep_x(const float* __restrict__ x, unsigned short* __restrict__ Xt){
    int b = blockIdx.x;
    int t = threadIdx.x;
    #pragma unroll
    for (int it = 0; it < 8; it++){
        int o = it * 256 + t;          // o = d*32 + m
        int d = o >> 5, m = o & 31;
        Xt[(size_t)b * 2048 + o] = f2bf(x[(size_t)b * 2048 + m * 64 + d]);
    }
}

__global__ void init_out(float* __restrict__ out, const float* __restrict__ fcb){
    int i = blockIdx.x * 256 + threadIdx.x;
    if (i < 1024) out[i] = fcb[0];
}

// Zm column swizzle: XOR the 64B-block bits with row&3 -> B-read banks uniform
// (8 words/bank, the b128 floor). Build-write chunk set per row is closed under
// this XOR -> write banks unchanged (uniform). shorts domain: bits 5,6.
#define SWZ(r) ((NN == 128) ? (((r) & 3) << 5) : 0)

// ---- fused CIN stage: h-in-regs, double-buffered swizzled Zm, 1 barrier/m ----
// Y[j][c] = sum_m sum_n W[(m,n)][j]*(x[c][m]*h[c][n]).  256 thr = 4 waves =
// 4 j-groups (j64), c=128 shared.  Per m: {per s: A2-prefetch(kt+1, L2) |
// 8 swizzled B-reads | 32 MFMA}; then build(m+1): CPQ coalesced-REG h chunks
// * xf -> ds_write Zm[next] (zero LDS reads); ONE barrier.  acc = pure MFMA
// C-chain (128 AGPR).  Arch regs: hreg 32 + A2 32 + Bf 16 + misc ~100 <= 128.
// LDS: Xlt 8192 + 2x34816 = 77824 B -> 2 blocks/CU.
#define CIN_MBODY(MM, P)                                                         \
    {                                                                            \
        unsigned short* const Zr = ((MM) & 1) ? Zm1 : Zm0;                       \
        unsigned short* const Zw = ((MM) & 1) ? Zm0 : Zm1;                       \
        const int mnext = (MM) + 1;                                              \
        _Pragma("unroll")                                                        \
        for (int s = 0; s < SB; s++){                                            \
            const int ktn = (MM) * SB + s + 1;                                   \
            if (ktn < KT){                                                       \
                _Pragma("unroll")                                                \
                for (int jt = 0; jt < 4; jt++)                                   \
                    A2[((P) + s + 1) & 1][jt] =                                  \
                        *(const bf16x8*)(wrow + (size_t)jt * 16 * KTOT + ktn * 32); \
            }                                                                    \
            _Pragma("unroll")                                                    \
            for (int ch = 0; ch < 2; ch++){                                      \
                bf16x8 Bf[4];                                                    \
                _Pragma("unroll")                                                \
                for (int cq = 0; cq < 4; cq++){                                  \
                    const int row = (((ch << 2) + cq) << 4) + li;                \
                    Bf[cq] = *(const bf16x8*)(Zr + row * ZS +                    \
                              ((((s) << 5) + (lq << 3)) ^ SWZ(row)));            \
                }                                                                \
                _Pragma("unroll")                                                \
                for (int cq = 0; cq < 4; cq++)                                   \
                    _Pragma("unroll")                                            \
                    for (int jt = 0; jt < 4; jt++)                               \
                        acc[jt][(ch << 2) + cq] =                                \
                            __builtin_amdgcn_mfma_f32_16x16x32_bf16(             \
                                A2[((P) + s) & 1][jt], Bf[cq],                   \
                                acc[jt][(ch << 2) + cq], 0, 0, 0);               \
            }                                                                    \
        }                                                                        \
        if (mnext < 32){                                                         \
            _Pragma("unroll")                                                    \
            for (int q = 0; q < CPQ; q++){                                       \
                const int row = rb + (q << RQS);                                 \
                float xf = bf2f(Xlt[mnext * 128 + row]);                         \
                uint4 hv = hreg[q];                                              \
                uint4 zv;                                                        \
                zv.x = mulpack(hv.x, xf);                                        \
                zv.y = mulpack(hv.y, xf);                                        \
                zv.z = mulpack(hv.z, xf);                                        \
                zv.w = mulpack(hv.w, xf);                                        \
                *(uint4*)(Zw + row * ZS + ((ncs << 3) ^ SWZ(row))) = zv;         \
            }                                                                    \
        }                                                                        \
        __syncthreads();                                                         \
    }

template<int NN, int KTOT, int JX, bool HAS_HOUT>
__global__ __launch_bounds__(256, 2) void cin_stage(
    const unsigned short* __restrict__ Xt,
    const unsigned short* __restrict__ Hin,
    const unsigned short* __restrict__ Wt,
    const float* __restrict__ bias,
    const float* __restrict__ fcW,      // pre-offset for this layer
    unsigned short* __restrict__ Hout,  // [b][d][n] bf16, n in [0,128); null if !HAS_HOUT
    float* __restrict__ out)
{
    constexpr int SB  = NN / 32;                 // kt per m
    constexpr int KT  = KTOT / 32;
    constexpr int ZS  = (NN == 32) ? 40 : 136;   // Zm row stride (shorts)
    constexpr int CPQ = NN / 16;                 // 16B chunks per thread
    constexpr int RQS = (NN == 128) ? 4 : 6;     // row step per q
    constexpr int LCR = (NN == 128) ? 4 : 2;     // log2(chunks per row)
    constexpr int ZMSZ = 128 * ZS;
    constexpr int NEED = 4096 + 2 * ZMSZ;
    constexpr int SMSZ = NEED > 17408 ? NEED : 17408;   // Yl overlay: 128*136

    __shared__ unsigned short smem[SMSZ];
    unsigned short* const Xlt = smem;            // [32][128] transposed x
    unsigned short* const Zm0 = smem + 4096;
    unsigned short* const Zm1 = Zm0 + ZMSZ;
    unsigned short* const Yl  = smem;            // epilogue overlay [n:128][c pad 136]

    const int t    = threadIdx.x;
    const int lane = t & 63;
    const int w    = t >> 6;        // 0..3 : j in [64w, 64w+64)
    const int li   = lane & 15;
    const int lq   = lane >> 4;
    const int rb   = t >> LCR;      // build row base
    const int ncs  = t & ((NN / 8) - 1);   // build chunk-in-row
    const int bpair = blockIdx.x;

    // ---- one-time staging: x transposed into Xlt[32][128] ----
    {
        const int c  = t >> 1;                  // 0..127
        const int mh = (t & 1) << 4;            // 16 shorts (m-range)
        const uint4* xsrc = (const uint4*)(Xt + (size_t)bpair * 4096 + c * 32 + mh);
        uint4 x0 = xsrc[0], x1 = xsrc[1];
        const unsigned short* xs0 = (const unsigned short*)&x0;
        const unsigned short* xs1 = (const unsigned short*)&x1;
        #pragma unroll
        for (int q = 0; q < 8; q++) Xlt[(mh + q) * 128 + c]     = xs0[q];
        #pragma unroll
        for (int q = 0; q < 8; q++) Xlt[(mh + 8 + q) * 128 + c] = xs1[q];
    }

    // ---- h chunks -> registers (coalesced: chunk g = t + 256q, addr = 16g) ----
    uint4 hreg[CPQ];
    {
        const unsigned short* hsrc0 = (NN == 128)
            ? (Hin + (size_t)bpair * 16384)
            : (Xt  + (size_t)bpair * 4096);
        #pragma unroll
        for (int q = 0; q < CPQ; q++)
            hreg[q] = *(const uint4*)(hsrc0 + (size_t)(t + (q << 8)) * 8);
    }
    __syncthreads();                 // Xlt visible

    // build(0) -> Zm0
    {
        #pragma unroll
        for (int q = 0; q < CPQ; q++){
            const int row = rb + (q << RQS);
            float xf = bf2f(Xlt[row]);           // m = 0
            uint4 hv = hreg[q];
            uint4 zv;
            zv.x = mulpack(hv.x, xf);
            zv.y = mulpack(hv.y, xf);
            zv.z = mulpack(hv.z, xf);
            zv.w = mulpack(hv.w, xf);
            *(uint4*)(Zm0 + row * ZS + ((ncs << 3) ^ SWZ(row))) = zv;
        }
    }

    // A fragments: lane reads Wt[j = 64w + jt*16 + li][kt*32 + lq*8 .. +8)
    const unsigned short* wrow = Wt + (size_t)((w << 6) + li) * KTOT + (lq << 3);
    bf16x8 A2[2][4];
    #pragma unroll
    for (int jt = 0; jt < 4; jt++)
        A2[0][jt] = *(const bf16x8*)(wrow + (size_t)jt * 16 * KTOT);

    f32x4 acc[4][8];   // pure MFMA C-chain -> AGPRs
    #pragma unroll
    for (int jt = 0; jt < 4; jt++)
        #pragma unroll
        for (int ct = 0; ct < 8; ct++)
            acc[jt][ct] = (f32x4){0.f, 0.f, 0.f, 0.f};

    __syncthreads();                 // Zm0(m=0) ready

    for (int m = 0; m < 32; m += 2){
        CIN_MBODY(m, 0);
        CIN_MBODY(m + 1, (SB & 1));
    }

    // epilogue: bias + relu; fc partial sums; stage h-half into Yl overlay
    // (last MBODY barrier guarantees all Zm/Xlt reads complete; Yl overlays dead LDS)
    float pfc0 = 0.f, pfc1 = 0.f;
    #pragma unroll
    for (int jt = 0; jt < 4; jt++){
        const int jb = (w << 6) + (jt << 4) + (lq << 2);
        float bv[4], fv[4];
        #pragma unroll
        for (int r = 0; r < 4; r++){
            int j = jb + r;
            bv[r] = bias[j];
            fv[r] = (j < JX) ? fcW[j] : 0.f;
        }
        #pragma unroll
        for (int ct = 0; ct < 8; ct++){
            f32x4 f = acc[jt][ct];
            int c = (ct << 4) + li;
            float ps = 0.f;
            #pragma unroll
            for (int r = 0; r < 4; r++){
                float y = f[r] + bv[r];
                y = y > 0.f ? y : 0.f;
                ps += fv[r] * y;
                if (HAS_HOUT){
                    int j = jb + r;
                    if (j >= 128)
                        Yl[(j - 128) * 136 + c] = f2bf(y);
                }
            }
            if (ct < 4) pfc0 += ps; else pfc1 += ps;
        }
    }
    #pragma unroll
    for (int off = 32; off; off >>= 1){
        pfc0 += __shfl_xor(pfc0, off, 64);
        pfc1 += __shfl_xor(pfc1, off, 64);
    }
    if (lane == 0){
        atomicAdd(out + bpair * 2 + 0, pfc0);
        atomicAdd(out + bpair * 2 + 1, pfc1);
    }

    if (HAS_HOUT){
        __syncthreads();
        // cooperative store: Hout[(bpair*128 + c)*128 + n] = Yl[n][c]
        const int c  = t >> 1;
        const int nh = (t & 1) << 6;           // 64 shorts per thread
        unsigned short* gdst = Hout + (size_t)(bpair * 128 + c) * 128 + nh;
        #pragma unroll
        for (int i8 = 0; i8 < 8; i8++){
            uint4 tv;
            unsigned short* tmp2 = (unsigned short*)&tv;
            #pragma unroll
            for (int q = 0; q < 8; q++)
                tmp2[q] = Yl[(nh + i8 * 8 + q) * 136 + c];
            *(uint4*)(gdst + i8 * 8) = tv;
        }
    }
}

extern "C" void kernel_launch(void* const* d_in, const int* in_sizes, int n_in,
                              void* d_out, int out_size, void* d_ws, size_t ws_size,
                              hipStream_t stream){
    const float* x   = (const float*)d_in[0];
    const float* W0  = (const float*)d_in[1];
    const float* b0  = (const float*)d_in[2];
    const float* W1  = (const float*)d_in[3];
    const float* b1  = (const float*)d_in[4];
    const float* W2  = (const float*)d_in[5];
    const float* b2  = (const float*)d_in[6];
    const float* fcW = (const float*)d_in[7];
    const float* fcb = (const float*)d_in[8];
    float* out = (float*)d_out;

    char* ws = (char*)d_ws;
    unsigned short* Xt  = (unsigned short*)(ws);             // 4 MB
    unsigned short* Wt0 = (unsigned short*)(ws + 4194304);   // 512 KB
    unsigned short* Wt1 = (unsigned short*)(ws + 4718592);   // 2 MB
    unsigned short* Wt2 = (unsigned short*)(ws + 6815744);   // 2 MB
    unsigned short* H0  = (unsigned short*)(ws + 8912896);   // 16 MB
    unsigned short* H1  = (unsigned short*)(ws + 25690112);  // 16 MB (end 42467328)

    prep_wt<<<dim3(16, 4), 256, 0, stream>>>(W0, Wt0, 1024);
    prep_wt<<<dim3(64, 4), 256, 0, stream>>>(W1, Wt1, 4096);
    prep_wt<<<dim3(64, 4), 256, 0, stream>>>(W2, Wt2, 4096);
    prep_x <<<1024, 256, 0, stream>>>(x, Xt);
    init_out<<<4, 256, 0, stream>>>(out, fcb);

    cin_stage< 32, 1024, 128, true ><<<512, 256, 0, stream>>>(Xt, Xt, Wt0, b0, fcW,       H0, out);
    cin_stage<128, 4096, 128, true ><<<512, 256, 0, stream>>>(Xt, H0, Wt1, b1, fcW + 128, H1, out);
    cin_stage<128, 4096, 256, false><<<512, 256, 0, stream>>>(Xt, H1, Wt2, b2, fcW + 256, nullptr, out);
}

// Round 14
// 689.119 us; speedup vs baseline: 1.1338x; 1.1338x over previous
//
#include <hip/hip_runtime.h>

typedef __attribute__((ext_vector_type(8))) short bf16x8;   // 8 bf16 = 4 VGPRs
typedef __attribute__((ext_vector_type(4))) float f32x4;    // MFMA C/D

__device__ __forceinline__ float bf2f(unsigned short u){
    unsigned int v = ((unsigned int)u) << 16;
    return __builtin_bit_cast(float, v);
}
__device__ __forceinline__ unsigned short f2bf(float f){
    unsigned int u = __builtin_bit_cast(unsigned int, f);
    u += 0x7FFFu + ((u >> 16) & 1u);   // RTNE (no NaN inputs here)
    return (unsigned short)(u >> 16);
}
// HW packed f32->bf16 RTNE (verified correct rounds 3/6/8/10)
__device__ __forceinline__ unsigned int cvt_pk_bf16(float lo, float hi){
    unsigned int r;
    asm("v_cvt_pk_bf16_f32 %0, %1, %2" : "=v"(r) : "v"(lo), "v"(hi));
    return r;
}
__device__ __forceinline__ unsigned int mulpack(unsigned int u, float xf){
    float flo = __builtin_bit_cast(float, u << 16);
    float fhi = __builtin_bit_cast(float, u & 0xffff0000u);
    return cvt_pk_bf16(xf * flo, xf * fhi);
}

// ---- prep: W (K x 256) fp32 -> Wt (256 x K) bf16, LDS-tiled transpose ----
__global__ void prep_wt(const float* __restrict__ W, unsigned short* __restrict__ Wt, int K){
    __shared__ float tile[64][65];
    const int k0 = blockIdx.x * 64;
    const int j0 = blockIdx.y * 64;
    const int t  = threadIdx.x;              // 256
    #pragma unroll
    for (int it = 0; it < 16; it++){
        int idx = it * 256 + t;
        int kr = idx >> 6, jc = idx & 63;
        tile[kr][jc] = W[(size_t)(k0 + kr) * 256 + j0 + jc];
    }
    __syncthreads();
    #pragma unroll
    for (int it = 0; it < 2; it++){
        int idx = it * 256 + t;
        int jr = idx >> 3, kc = (idx & 7) << 3;
        uint4 tv;
        unsigned short* ts = (unsigned short*)&tv;
        #pragma unroll
        for (int q = 0; q < 8; q++)
            ts[q] = f2bf(tile[kc + q][jr]);
        *(uint4*)(Wt + (size_t)(j0 + jr) * K + k0 + kc) = tv;
    }
}

// ---- prep: x (b,m,d) fp32 -> Xt[b][d][m] bf16 ----
__global__ void prep_x(const float* __restrict__ x, unsigned short* __restrict__ Xt){
    int b = blockIdx.x;
    int t = threadIdx.x;
    #pragma unroll
    for (int it = 0; it < 8; it++){
        int o = it * 256 + t;          // o = d*32 + m
        int d = o >> 5, m = o & 31;
        Xt[(size_t)b * 2048 + o] = f2bf(x[(size_t)b * 2048 + m * 64 + d]);
    }
}

__global__ void init_out(float* __restrict__ out, const float* __restrict__ fcb){
    int i = blockIdx.x * 256 + threadIdx.x;
    if (i < 1024) out[i] = fcb[0];
}

// ---- fused CIN stage: cooperative Z-tile + pure GEMM, wave tile j128 x c64 ----
// r10 skeleton (verified) with the wave map reshaped: 4 waves = 2 jg x 2 cg.
// Wave output = j128 x c64 -> each wave reads only its c64 half of Zm:
// B-read LDS traffic HALVES vs r10 (the measured dominant LDS term).
// A: per-kt ping-pong A2[2][8] prefetched one kt (~640 cy) ahead from L2
// (W 2x read redundancy -> 2 GB L2 chip-wide ~58 us, under the 67 us matrix
// floor; HBM unchanged). acc[8][4] = 128 AGPR pure MFMA C-chain. Arch regs
// ~105 <= 128. Build/barriers/staging identical to r10. LDS 79872 B -> 2 blk/CU.
#define CIN_MBODY(MM, P)                                                         \
    {                                                                            \
        const int mnext = (MM) + 1;                                              \
        _Pragma("unroll")                                                        \
        for (int s = 0; s < SB; s++){                                            \
            const int ktn = (MM) * SB + s + 1;                                   \
            if (ktn < KT){                                                       \
                _Pragma("unroll")                                                \
                for (int jt = 0; jt < 8; jt++)                                   \
                    A2[((P) + s + 1) & 1][jt] =                                  \
                        *(const bf16x8*)(wrow + (size_t)jt * 16 * KTOT + ktn * 32); \
            }                                                                    \
            bf16x8 Bf[4];                                                        \
            _Pragma("unroll")                                                    \
            for (int ct = 0; ct < 4; ct++)                                       \
                Bf[ct] = *(const bf16x8*)(Zm + (cgo + (ct << 4) + li) * ZS + (s << 5) + (lq << 3)); \
            _Pragma("unroll")                                                    \
            for (int ct = 0; ct < 4; ct++)                                       \
                _Pragma("unroll")                                                 \
                for (int jt = 0; jt < 8; jt++)                                   \
                    acc[jt][ct] = __builtin_amdgcn_mfma_f32_16x16x32_bf16(       \
                        A2[((P) + s) & 1][jt], Bf[ct], acc[jt][ct], 0, 0, 0);    \
        }                                                                        \
        __syncthreads();             /* all reads of Zm(MM) done */              \
        if (mnext < 32) build(mnext);                                            \
        __syncthreads();             /* Zm(mnext) ready */                       \
    }

template<int NN, int KTOT, int JX, bool HAS_HOUT>
__global__ __launch_bounds__(256, 2) void cin_stage(
    const unsigned short* __restrict__ Xt,
    const unsigned short* __restrict__ Hin,
    const unsigned short* __restrict__ Wt,
    const float* __restrict__ bias,
    const float* __restrict__ fcW,      // pre-offset for this layer
    unsigned short* __restrict__ Hout,  // [b][d][n] bf16, n in [0,128); null if !HAS_HOUT
    float* __restrict__ out)
{
    constexpr int SB  = NN / 32;                 // kt per m
    constexpr int KT  = KTOT / 32;
    constexpr int XS  = 40;                      // Xl row stride (shorts)
    constexpr int ZS  = (NN == 32) ? XS : 136;   // Hl / Zm row stride (shorts)
    constexpr int XLSZ = 128 * XS;               // 5120 shorts
    constexpr int HLSZ = (NN == 32) ? 0 : 128 * ZS;
    constexpr int ZMSZ = 128 * ZS;
    constexpr int NEED = XLSZ + HLSZ + ZMSZ;
    constexpr int SMSZ = NEED > 17408 ? NEED : 17408;   // Yl overlay: 128*136

    __shared__ unsigned short smem[SMSZ];
    unsigned short* const Xl = smem;
    unsigned short* const Hl = (NN == 32) ? smem : (smem + XLSZ);   // h == x for stage 0
    unsigned short* const Zm = smem + XLSZ + HLSZ;
    unsigned short* const Yl = smem;             // epilogue overlay [n:128][c pad 136]

    const int t    = threadIdx.x;
    const int lane = t & 63;
    const int w    = t >> 6;        // 0..3
    const int jg   = w & 1;         // j-group: j in [128*jg, 128*jg+128)
    const int cg   = w >> 1;        // c-group: c in [64*cg, 64*cg+64)
    const int li   = lane & 15;
    const int lq   = lane >> 4;
    const int cgo  = cg << 6;
    const int bpair = blockIdx.x;

    // ---- one-time staging: x -> Xl row-major; h -> Hl row-major (r10-identical) ----
    {
        const int c  = t >> 1;                  // 0..127
        const int b  = bpair * 2 + (c >> 6);
        const int d  = c & 63;
        const int half = t & 1;
        const int mh = half << 4;               // 16 shorts per thread
        const uint4* xsrc = (const uint4*)(Xt + ((size_t)b << 11) + (d << 5) + mh);
        uint4 x0 = xsrc[0], x1 = xsrc[1];
        *(uint4*)(Xl + c * XS + mh)     = x0;
        *(uint4*)(Xl + c * XS + mh + 8) = x1;
        if (NN == 128){
            const int nh = half << 6;           // 64 shorts per thread
            const uint4* hsrc = (const uint4*)(Hin + (size_t)((b << 6) + d) * 128 + nh);
            #pragma unroll
            for (int q = 0; q < 8; q++){
                uint4 hv = hsrc[q];
                *(uint4*)(Hl + c * ZS + nh + q * 8) = hv;
            }
        }
    }

    // cooperative Zm build (r10-identical): thread owns row c = t&127, half bh
    const int bc = t & 127;
    const int bh = t >> 7;                      // 0..1
    constexpr int CPT = (NN == 128) ? 8 : 2;    // 16B chunks per thread
    auto build = [&](int m){
        float xf = bf2f(Xl[bc * XS + m]);
        #pragma unroll
        for (int j = 0; j < CPT; j++){
            int off = (bh * CPT + j) << 3;      // shorts
            uint4 hv = *(const uint4*)(Hl + bc * ZS + off);
            uint4 zv;
            zv.x = mulpack(hv.x, xf);
            zv.y = mulpack(hv.y, xf);
            zv.z = mulpack(hv.z, xf);
            zv.w = mulpack(hv.w, xf);
            *(uint4*)(Zm + bc * ZS + off) = zv;
        }
    };

    // A fragments: lane reads Wt[j = 128*jg + jt*16 + li][kt*32 + lq*8 .. +8)
    const unsigned short* wrow = Wt + (size_t)((jg << 7) + li) * KTOT + (lq << 3);
    bf16x8 A2[2][8];
    #pragma unroll
    for (int jt = 0; jt < 8; jt++)
        A2[0][jt] = *(const bf16x8*)(wrow + (size_t)jt * 16 * KTOT);

    f32x4 acc[8][4];   // pure MFMA C-chain over all kt -> 128 AGPRs
    #pragma unroll
    for (int jt = 0; jt < 8; jt++)
        #pragma unroll
        for (int ct = 0; ct < 4; ct++)
            acc[jt][ct] = (f32x4){0.f, 0.f, 0.f, 0.f};

    __syncthreads();                 // staging done
    build(0);
    __syncthreads();                 // Zm(0) ready

    for (int m = 0; m < 32; m += 2){
        CIN_MBODY(m, 0);
        CIN_MBODY(m + 1, (SB & 1));
    }

    // epilogue: bias + relu; fc partial (wave's c64 lies in ONE batch elem = cg);
    // stage h-half into Yl overlay (j>=128 held by jg=1 waves)
    float pfc = 0.f;
    #pragma unroll
    for (int jt = 0; jt < 8; jt++){
        const int jb = (jg << 7) + (jt << 4) + (lq << 2);
        float bv[4], fv[4];
        #pragma unroll
        for (int r = 0; r < 4; r++){
            int j = jb + r;
            bv[r] = bias[j];
            fv[r] = (j < JX) ? fcW[j] : 0.f;
        }
        #pragma unroll
        for (int ct = 0; ct < 4; ct++){
            f32x4 f = acc[jt][ct];
            int c = cgo + (ct << 4) + li;
            #pragma unroll
            for (int r = 0; r < 4; r++){
                float y = f[r] + bv[r];
                y = y > 0.f ? y : 0.f;
                pfc += fv[r] * y;
                if (HAS_HOUT){
                    int j = jb + r;
                    if (j >= 128)
                        Yl[(j - 128) * 136 + c] = f2bf(y);
                }
            }
        }
    }
    #pragma unroll
    for (int off = 32; off; off >>= 1)
        pfc += __shfl_xor(pfc, off, 64);
    if (lane == 0)
        atomicAdd(out + bpair * 2 + cg, pfc);

    if (HAS_HOUT){
        __syncthreads();
        // cooperative store: Hout[(bpair*128 + c)*128 + n] = Yl[n][c]
        const int c  = t >> 1;
        const int nh = (t & 1) << 6;           // 64 shorts per thread
        unsigned short* gdst = Hout + (size_t)(bpair * 128 + c) * 128 + nh;
        #pragma unroll
        for (int i8 = 0; i8 < 8; i8++){
            uint4 tv;
            unsigned short* tmp2 = (unsigned short*)&tv;
            #pragma unroll
            for (int q = 0; q < 8; q++)
                tmp2[q] = Yl[(nh + i8 * 8 + q) * 136 + c];
            *(uint4*)(gdst + i8 * 8) = tv;
        }
    }
}

extern "C" void kernel_launch(void* const* d_in, const int* in_sizes, int n_in,
                              void* d_out, int out_size, void* d_ws, size_t ws_size,
                              hipStream_t stream){
    const float* x   = (const float*)d_in[0];
    const float* W0  = (const float*)d_in[1];
    const float* b0  = (const float*)d_in[2];
    const float* W1  = (const float*)d_in[3];
    const float* b1  = (const float*)d_in[4];
    const float* W2  = (const float*)d_in[5];
    const float* b2  = (const float*)d_in[6];
    const float* fcW = (const float*)d_in[7];
    const float* fcb = (const float*)d_in[8];
    float* out = (float*)d_out;

    char* ws = (char*)d_ws;
    unsigned short* Xt  = (unsigned short*)(ws);             // 4 MB
    unsigned short* Wt0 = (unsigned short*)(ws + 4194304);   // 512 KB
    unsigned short* Wt1 = (unsigned short*)(ws + 4718592);   // 2 MB
    unsigned short* Wt2 = (unsigned short*)(ws + 6815744);   // 2 MB
    unsigned short* H0  = (unsigned short*)(ws + 8912896);   // 16 MB
    unsigned short* H1  = (unsigned short*)(ws + 25690112);  // 16 MB (end 42467328)

    prep_wt<<<dim3(16, 4), 256, 0, stream>>>(W0, Wt0, 1024);
    prep_wt<<<dim3(64, 4), 256, 0, stream>>>(W1, Wt1, 4096);
    prep_wt<<<dim3(64, 4), 256, 0, stream>>>(W2, Wt2, 4096);
    prep_x <<<1024, 256, 0, stream>>>(x, Xt);
    init_out<<<4, 256, 0, stream>>>(out, fcb);

    cin_stage< 32, 1024, 128, true ><<<512, 256, 0, stream>>>(Xt, Xt, Wt0, b0, fcW,       H0, out);
    cin_stage<128, 4096, 128, true ><<<512, 256, 0, stream>>>(Xt, H0, Wt1, b1, fcW + 128, H1, out);
    cin_stage<128, 4096, 256, false><<<512, 256, 0, stream>>>(Xt, H1, Wt2, b2, fcW + 256, nullptr, out);
}

// Round 15
// 383.321 us; speedup vs baseline: 2.0383x; 1.7978x over previous
//
#include <hip/hip_runtime.h>

typedef __attribute__((ext_vector_type(8))) short bf16x8;   // 8 bf16 = 4 VGPRs
typedef __attribute__((ext_vector_type(4))) float f32x4;    // MFMA C/D

__device__ __forceinline__ float bf2f(unsigned short u){
    unsigned int v = ((unsigned int)u) << 16;
    return __builtin_bit_cast(float, v);
}
__device__ __forceinline__ unsigned short f2bf(float f){
    unsigned int u = __builtin_bit_cast(unsigned int, f);
    u += 0x7FFFu + ((u >> 16) & 1u);   // RTNE (no NaN inputs here)
    return (unsigned short)(u >> 16);
}
// HW packed f32->bf16 RTNE (verified rounds 3/6/8/10/13/14: absmax identical)
__device__ __forceinline__ unsigned int cvt_pk_bf16(float lo, float hi){
    unsigned int r;
    asm("v_cvt_pk_bf16_f32 %0, %1, %2" : "=v"(r) : "v"(lo), "v"(hi));
    return r;
}
__device__ __forceinline__ unsigned int mulpack(unsigned int u, float xf){
    float flo = __builtin_bit_cast(float, u << 16);
    float fhi = __builtin_bit_cast(float, u & 0xffff0000u);
    return cvt_pk_bf16(xf * flo, xf * fhi);
}

// ---- prep: W (K x 256) fp32 -> Wt (256 x K) bf16, LDS-tiled transpose ----
// (verified in rounds 8/10/13/14)
__global__ void prep_wt(const float* __restrict__ W, unsigned short* __restrict__ Wt, int K){
    __shared__ float tile[64][65];
    const int k0 = blockIdx.x * 64;
    const int j0 = blockIdx.y * 64;
    const int t  = threadIdx.x;              // 256
    #pragma unroll
    for (int it = 0; it < 16; it++){
        int idx = it * 256 + t;
        int kr = idx >> 6, jc = idx & 63;
        tile[kr][jc] = W[(size_t)(k0 + kr) * 256 + j0 + jc];
    }
    __syncthreads();
    #pragma unroll
    for (int it = 0; it < 2; it++){
        int idx = it * 256 + t;
        int jr = idx >> 3, kc = (idx & 7) << 3;
        uint4 tv;
        unsigned short* ts = (unsigned short*)&tv;
        #pragma unroll
        for (int q = 0; q < 8; q++)
            ts[q] = f2bf(tile[kc + q][jr]);
        *(uint4*)(Wt + (size_t)(j0 + jr) * K + k0 + kc) = tv;
    }
}

// ---- prep: x (b,m,d) fp32 -> Xt[b][d][m] bf16 ----
__global__ void prep_x(const float* __restrict__ x, unsigned short* __restrict__ Xt){
    int b = blockIdx.x;
    int t = threadIdx.x;
    #pragma unroll
    for (int it = 0; it < 8; it++){
        int o = it * 256 + t;          // o = d*32 + m
        int d = o >> 5, m = o & 31;
        Xt[(size_t)b * 2048 + o] = f2bf(x[(size_t)b * 2048 + m * 64 + d]);
    }
}

__global__ void init_out(float* __restrict__ out, const float* __restrict__ fcb){
    int i = blockIdx.x * 256 + threadIdx.x;
    if (i < 1024) out[i] = fcb[0];
}

// ---- fused CIN stage (round-0 structure, verified 154.8 us/stage) ----
// Z[k=(m,n), c=(bb,d)] = x[c][m] * h[c][n]; x,h persist in LDS; Z double-buffered,
// ONE barrier per kt; build(kt+1) overlaps MFMA(kt) in the issue stream.
// ONLY hot-loop change vs round 0: build uses HW v_cvt_pk_bf16_f32 (mulpack),
// 2.5 VALU/elem vs 5 -> halves the measured-dominant build-VALU (VALUBusy 40.5%).
// Block: 128 c (2 batch elems), 4 waves, j in [64w, 64w+64).
template<int NN, int LOG2NN, int KTOT, int JX, bool HAS_HOUT>
__global__ __launch_bounds__(256, 2) void cin_stage(
    const unsigned short* __restrict__ Xt,
    const unsigned short* __restrict__ Hin,
    const unsigned short* __restrict__ Wt,
    const float* __restrict__ bias,
    const float* __restrict__ fcW,      // pre-offset for this layer
    unsigned short* __restrict__ Hout,  // [b][d][n] bf16, n in [0,128); null if !HAS_HOUT
    float* __restrict__ out)
{
    constexpr int KT = KTOT / 32;
    constexpr int ZS = 40;                      // Z row stride (shorts), 80B: b128-aligned
    constexpr int XS = 40;                      // Xl row stride
    constexpr int HS = (NN == 32) ? XS : 136;   // Hl row stride (272B: b128-aligned)

    __shared__ unsigned short smem[32768];      // 64 KB
    unsigned short* const Zb0 = smem;                       // [128][40]  10240 B
    unsigned short* const Zb1 = smem + 5120;                // [128][40]  10240 B
    unsigned short* const Xl  = smem + 10240;               // [128][40]  10240 B
    unsigned short* const Hl  = (NN == 32) ? Xl : (smem + 15360);  // [128][136] 34816 B
    unsigned short* const Yl  = smem + 15360;               // epilogue overlay [n:128][c pad 136]

    const int t    = threadIdx.x;
    const int lane = t & 63;
    const int w    = t >> 6;
    const int li   = lane & 15;
    const int lq   = lane >> 4;
    const int bpair = blockIdx.x;

    // ---- one-time staging of x (and h) into LDS, fully coalesced ----
    {
        const int c  = t >> 1;
        const int b  = bpair * 2 + (c >> 6);
        const int d  = c & 63;
        const int mh = (t & 1) << 4;            // 16 shorts per thread
        const uint4* xsrc = (const uint4*)(Xt + ((size_t)b << 11) + (d << 5) + mh);
        uint4 x0 = xsrc[0], x1 = xsrc[1];
        *(uint4*)(Xl + c * XS + mh)     = x0;
        *(uint4*)(Xl + c * XS + mh + 8) = x1;
        if (NN == 128){
            const int nh = (t & 1) << 6;        // 64 shorts per thread
            const uint4* hsrc = (const uint4*)(Hin + (size_t)((b << 6) + d) * 128 + nh);
            #pragma unroll
            for (int q = 0; q < 8; q++){
                uint4 hv = hsrc[q];
                *(uint4*)(Hl + c * HS + nh + q * 8) = hv;
            }
        }
    }
    __syncthreads();

    // Z-build: thread fills Zb[zc][zkh*16 .. +16) from LDS x,h — HW cvt_pk path
    const int zc  = t & 127;
    const int zkh = t >> 7;
    auto build = [&](unsigned short* zbuf, int kt){
        const int kg = (kt << 5) + (zkh << 4);
        const int m  = kg >> LOG2NN;
        const int n0 = kg & (NN - 1);
        float xf = bf2f(Xl[zc * XS + m]);
        const uint4* hsrc = (const uint4*)(Hl + zc * HS + n0);
        uint4 h0 = hsrc[0], h1 = hsrc[1];
        uint4 z0, z1;
        z0.x = mulpack(h0.x, xf);
        z0.y = mulpack(h0.y, xf);
        z0.z = mulpack(h0.z, xf);
        z0.w = mulpack(h0.w, xf);
        z1.x = mulpack(h1.x, xf);
        z1.y = mulpack(h1.y, xf);
        z1.z = mulpack(h1.z, xf);
        z1.w = mulpack(h1.w, xf);
        uint4* zdst = (uint4*)(zbuf + zc * ZS + (zkh << 4));
        zdst[0] = z0;
        zdst[1] = z1;
    };

    // A-fragments: lane reads Wt[j = w*64 + jt*16 + li][kt*32 + lq*8 .. +8)
    const unsigned short* wbase = Wt + (size_t)((w << 6) + li) * KTOT + (lq << 3);
    auto loadA = [&](int kt, bf16x8* A){
        const unsigned short* wk = wbase + (kt << 5);
        #pragma unroll
        for (int jt = 0; jt < 4; jt++)
            A[jt] = *(const bf16x8*)(wk + (size_t)jt * 16 * KTOT);
    };

    f32x4 acc[4][8];
    #pragma unroll
    for (int jt = 0; jt < 4; jt++)
        #pragma unroll
        for (int ct = 0; ct < 8; ct++)
            acc[jt][ct] = (f32x4){0.f, 0.f, 0.f, 0.f};

    // prologue: Z(0) into buf0, A(0) into regs
    build(Zb0, 0);
    bf16x8 Acur[4];
    loadA(0, Acur);
    __syncthreads();

    for (int kt = 0; kt < KT; kt++){
        unsigned short* const Zr = (kt & 1) ? Zb1 : Zb0;   // read buf
        unsigned short* const Zw = (kt & 1) ? Zb0 : Zb1;   // write buf (for kt+1)
        bf16x8 Anx[4];
        loadA(kt + 1 < KT ? kt + 1 : kt, Anx);             // prefetch next A
        #pragma unroll
        for (int ct = 0; ct < 8; ct++){
            bf16x8 B = *(const bf16x8*)(Zr + ((ct << 4) + li) * ZS + (lq << 3));
            #pragma unroll
            for (int jt = 0; jt < 4; jt++)
                acc[jt][ct] = __builtin_amdgcn_mfma_f32_16x16x32_bf16(Acur[jt], B, acc[jt][ct], 0, 0, 0);
        }
        if (kt + 1 < KT) build(Zw, kt + 1);                // MFMA pipe hides this
        #pragma unroll
        for (int jt = 0; jt < 4; jt++) Acur[jt] = Anx[jt];
        __syncthreads();                                   // the only barrier per kt
    }

    // epilogue: bias + relu; fc partial sums; stage h-half into Yl
    float pfc0 = 0.f, pfc1 = 0.f;
    #pragma unroll
    for (int jt = 0; jt < 4; jt++){
        const int jb = (w << 6) + (jt << 4) + (lq << 2);
        float bv[4], fv[4];
        #pragma unroll
        for (int r = 0; r < 4; r++){
            int j = jb + r;
            bv[r] = bias[j];
            fv[r] = (j < JX) ? fcW[j] : 0.f;
        }
        #pragma unroll
        for (int ct = 0; ct < 8; ct++){
            f32x4 f = acc[jt][ct];
            int c = (ct << 4) + li;
            float ps = 0.f;
            #pragma unroll
            for (int r = 0; r < 4; r++){
                float y = f[r] + bv[r];
                y = y > 0.f ? y : 0.f;
                ps += fv[r] * y;
                if (HAS_HOUT){
                    int j = jb + r;
                    if (j >= 128)
                        Yl[(j - 128) * 136 + c] = f2bf(y);
                }
            }
            if (ct < 4) pfc0 += ps; else pfc1 += ps;
        }
    }
    #pragma unroll
    for (int off = 32; off; off >>= 1){
        pfc0 += __shfl_xor(pfc0, off, 64);
        pfc1 += __shfl_xor(pfc1, off, 64);
    }
    if (lane == 0){
        atomicAdd(out + bpair * 2 + 0, pfc0);
        atomicAdd(out + bpair * 2 + 1, pfc1);
    }

    if (HAS_HOUT){
        __syncthreads();
        // cooperative store: Hout[(bpair*128 + c)*128 + n] = Yl[n][c]
        const int c  = t >> 1;
        const int nh = (t & 1) << 6;
        unsigned short* gdst = Hout + (size_t)(bpair * 128 + c) * 128 + nh;
        #pragma unroll
        for (int i8 = 0; i8 < 8; i8++){
            uint4 tv;
            unsigned short* tmp = (unsigned short*)&tv;
            #pragma unroll
            for (int q = 0; q < 8; q++)
                tmp[q] = Yl[(nh + i8 * 8 + q) * 136 + c];
            *(uint4*)(gdst + i8 * 8) = tv;
        }
    }
}

extern "C" void kernel_launch(void* const* d_in, const int* in_sizes, int n_in,
                              void* d_out, int out_size, void* d_ws, size_t ws_size,
                              hipStream_t stream){
    const float* x   = (const float*)d_in[0];
    const float* W0  = (const float*)d_in[1];
    const float* b0  = (const float*)d_in[2];
    const float* W1  = (const float*)d_in[3];
    const float* b1  = (const float*)d_in[4];
    const float* W2  = (const float*)d_in[5];
    const float* b2  = (const float*)d_in[6];
    const float* fcW = (const float*)d_in[7];
    const float* fcb = (const float*)d_in[8];
    float* out = (float*)d_out;

    char* ws = (char*)d_ws;
    unsigned short* Xt  = (unsigned short*)(ws);             // 4 MB
    unsigned short* Wt0 = (unsigned short*)(ws + 4194304);   // 512 KB
    unsigned short* Wt1 = (unsigned short*)(ws + 4718592);   // 2 MB
    unsigned short* Wt2 = (unsigned short*)(ws + 6815744);   // 2 MB
    unsigned short* H0  = (unsigned short*)(ws + 8912896);   // 16 MB
    unsigned short* H1  = (unsigned short*)(ws + 25690112);  // 16 MB (end 42467328)

    prep_wt<<<dim3(16, 4), 256, 0, stream>>>(W0, Wt0, 1024);
    prep_wt<<<dim3(64, 4), 256, 0, stream>>>(W1, Wt1, 4096);
    prep_wt<<<dim3(64, 4), 256, 0, stream>>>(W2, Wt2, 4096);
    prep_x <<<1024, 256, 0, stream>>>(x, Xt);
    init_out<<<4, 256, 0, stream>>>(out, fcb);

    cin_stage< 32, 5, 1024, 128, true ><<<512, 256, 0, stream>>>(Xt, Xt, Wt0, b0, fcW,       H0, out);
    cin_stage<128, 7, 4096, 128, true ><<<512, 256, 0, stream>>>(Xt, H0, Wt1, b1, fcW + 128, H1, out);
    cin_stage<128, 7, 4096, 256, false><<<512, 256, 0, stream>>>(Xt, H1, Wt2, b2, fcW + 256, nullptr, out);
}